// Round 18
// baseline (2081.197 us; speedup 1.0000x reference)
//
#include <hip/hip_runtime.h>
#include <math.h>

#define EMBD 128
#define HIDD 128
#define NTAR 16
#define BSEQ 4096
#define G4   512
#define CH   8            // zx load / hs store batch (amortizes barrier cost)

typedef _Float16 v8h __attribute__((ext_vector_type(8)));
typedef float    v4f __attribute__((ext_vector_type(4)));

__device__ __forceinline__ float fast_sigmoid(float z) {
    return __builtin_amdgcn_rcpf(1.f + __expf(-z));
}
__device__ __forceinline__ float fast_tanh(float z) {
    return 1.f - 2.f * __builtin_amdgcn_rcpf(1.f + __expf(2.f * z));
}

// Raw workgroup barrier WITHOUT the __syncthreads vmcnt(0) drain.
// Cross-wave dependency per step is ONLY h_db (LDS): lgkmcnt(0) before
// s_barrier orders ds_write -> barrier -> ds_read. Global zx prefetch
// loads / hs stores stay in flight across the barrier.
// SAFETY: R4 vs R5 (bar_lds vs __syncthreads, same kernel) produced
// bit-identical output trajectories -> no race; R11 PASSED with this.
__device__ __forceinline__ void bar_lds() {
    asm volatile("s_waitcnt lgkmcnt(0)" ::: "memory");
    __builtin_amdgcn_s_barrier();
    asm volatile("" ::: "memory");
}

// ---------------------------------------------------------------------------
// Kernel 1: input projection, transposed layout (fp32 — zx precision anchor).
// zxT[(t*128 + u)*4 + g] = dot(emb[x[t]], w_ih[g*128+u]) + b_ih + b_hh
// ---------------------------------------------------------------------------
__global__ void input_proj_kernel(const int* __restrict__ x,
                                  const float* __restrict__ emb,
                                  const float* __restrict__ w_ih,
                                  const float* __restrict__ b_ih,
                                  const float* __restrict__ b_hh,
                                  float* __restrict__ zxT) {
    const int t = blockIdx.x;
    const int j = threadIdx.x;            // 0..511
    const int u = j >> 2;
    const int g = j & 3;
    const int row = g * HIDD + u;
    const int idx = x[t];
    const float4* __restrict__ er = (const float4*)(emb + (long long)idx * EMBD);
    const float4* __restrict__ wr = (const float4*)(w_ih + row * EMBD);
    float acc = 0.f;
#pragma unroll
    for (int k = 0; k < EMBD / 4; ++k) {
        float4 e = er[k];
        float4 w = wr[k];
        acc += e.x * w.x + e.y * w.y + e.z * w.z + e.w * w.w;
    }
    zxT[(t * HIDD + u) * 4 + g] = acc + b_ih[row] + b_hh[row];
}

// ---------------------------------------------------------------------------
// Kernel 2: sequential LSTM via MFMA. 512 threads (8 waves, 2/SIMD).
// FINAL VERIFIED CONFIGURATION (R11: 2078 µs total, absmax 4.9e-4).
//
// Session post-mortem (R0-R17): step = 1072 cyc = 620 cyc geometry-forced
// matrix-pipe occupancy (128 MFMAs/step: M=1 matvec on 16x16 min-shape,
// any f16 MFMA shape gives the same count) + ~450 cyc serial latency
// (LDS h round-trip ~200, gate transcendental chain ~100, tail) that
// barrier-lockstep prevents overlapping. Attempted levers:
//  - bar_lds + depth-2 chains: safe, neutral (R11) — kept.
//  - MFMA/VALU pipe-role hybrid (the ~40% lever): ABANDONED — the VALU
//    dot deviates from the verified MFMA value by O(z) deterministically
//    (R14/R17 in-situ comparators: own-dot dirty ~0.04, no shfl involved);
//    13 audits + 3 runtime probes could not localize a fixable cause.
//
// Wave w owns units [16w, 16w+16). B-frag (g,q), lane (n=l&15, qd=l>>4):
//   B[k=q*32+qd*8+j][n] = W_hh[g*128+U0+n][q*32+qd*8+j]  (8 f16, pinned).
// A-frag q: row 0 = h only; leaders (l&15==0) read h slices, other lanes
// read a zeroed 16B pad -> rows 1..15 zero free. D layout (m89): col=l&15,
// row=(l>>4)*4+reg -> row 0 in lanes 0..15 reg 0; gates stay in-lane.
// One barrier/step; h_db double-buffered on step parity; CH=8 batching.
// ---------------------------------------------------------------------------
__global__ __launch_bounds__(512, 2)
void lstm_seq_kernel(const float* __restrict__ zxT,
                     const float* __restrict__ w_hh,
                     float* __restrict__ hs) {
    __shared__ __align__(16) _Float16 h_db[2][HIDD];
    __shared__ __align__(16) _Float16 zpad[8];    // stays zero forever

    const int tid = threadIdx.x;
    const int l   = tid & 63;
    const int wv  = tid >> 6;            // 0..7
    const int n   = l & 15;              // unit-sub / MFMA col
    const int qd  = l >> 4;              // quad id 0..3
    const int U0  = wv * 16;             // this wave's unit block
    const int u   = U0 + n;
    const bool lane16 = (l < 16);        // holds valid z/h (row 0 lanes)

    // B-fragments: b[g][q], 8 f16 each = 64 VGPRs total. Pinned.
    v8h b[4][4];
#pragma unroll
    for (int g = 0; g < 4; ++g) {
#pragma unroll
        for (int q = 0; q < 4; ++q) {
            const float* __restrict__ wr =
                w_hh + (g * HIDD + u) * HIDD + q * 32 + qd * 8;
            v8h f;
#pragma unroll
            for (int j = 0; j < 8; ++j) f[j] = (_Float16)wr[j];
            b[g][q] = f;
        }
    }
#pragma unroll
    for (int g = 0; g < 4; ++g)
#pragma unroll
        for (int q = 0; q < 4; ++q)
            asm volatile("" : "+v"(b[g][q]));     // no rematerialization

    if (tid < HIDD) { h_db[0][tid] = (_Float16)0.f; h_db[1][tid] = (_Float16)0.f; }
    if (tid < 8)    zpad[tid] = (_Float16)0.f;

    // A-frag source addresses: leader lanes walk h, others pinned at zpad.
    const bool leader = (n == 0);
    const _Float16* abase0 = leader ? &h_db[0][qd * 8] : &zpad[0];
    const _Float16* abase1 = leader ? &h_db[1][qd * 8] : &zpad[0];
    const int astep = leader ? 32 : 0;            // halves per K-chunk

    float c = 0.f;
    float hreg[CH];
    float4 zcur[CH], zfut[CH];
    const float4* __restrict__ zx4 = (const float4*)zxT;
#pragma unroll
    for (int s = 0; s < CH; ++s) {
        zcur[s] = zx4[s * HIDD + u];     // lanes 16-63 duplicate lane n
        hreg[s] = 0.f;
    }
    __syncthreads();                     // init barrier: full drain is fine

    const v4f vz = {0.f, 0.f, 0.f, 0.f};

    for (int tc = 0; tc < BSEQ; tc += CH) {
        // Batch-store previous chunk's h (16 lanes/wave, coalesced 64B).
        if (lane16 && tc > 0) {
#pragma unroll
            for (int s = 0; s < CH; ++s)
                hs[(tc - CH + s) * HIDD + u] = hreg[s];
        }
        // Prefetch NEXT chunk's zx rows (stay in flight across bar_lds).
        {
            const int tn = (tc + CH < BSEQ) ? (tc + CH) : (BSEQ - CH);
#pragma unroll
            for (int s = 0; s < CH; ++s)
                zfut[s] = zx4[(tn + s) * HIDD + u];
        }

#pragma unroll
        for (int s = 0; s < CH; ++s) {
            const _Float16* ab = (s & 1) ? abase1 : abase0;
            const int wb = (s & 1) ^ 1;

            // A-frags: leaders read h slices, others read the zero pad.
            v8h a0 = *(const v8h*)(ab + 0 * astep);
            v8h a1 = *(const v8h*)(ab + 1 * astep);
            v8h a2 = *(const v8h*)(ab + 2 * astep);
            v8h a3 = *(const v8h*)(ab + 3 * astep);

            // 16 MFMAs: 4 gates x two depth-2 K-chains (8 indep chains).
            v4f dA0 = __builtin_amdgcn_mfma_f32_16x16x32_f16(a0, b[0][0], vz, 0, 0, 0);
            v4f dA1 = __builtin_amdgcn_mfma_f32_16x16x32_f16(a0, b[1][0], vz, 0, 0, 0);
            v4f dA2 = __builtin_amdgcn_mfma_f32_16x16x32_f16(a0, b[2][0], vz, 0, 0, 0);
            v4f dA3 = __builtin_amdgcn_mfma_f32_16x16x32_f16(a0, b[3][0], vz, 0, 0, 0);
            v4f dB0 = __builtin_amdgcn_mfma_f32_16x16x32_f16(a2, b[0][2], vz, 0, 0, 0);
            v4f dB1 = __builtin_amdgcn_mfma_f32_16x16x32_f16(a2, b[1][2], vz, 0, 0, 0);
            v4f dB2 = __builtin_amdgcn_mfma_f32_16x16x32_f16(a2, b[2][2], vz, 0, 0, 0);
            v4f dB3 = __builtin_amdgcn_mfma_f32_16x16x32_f16(a2, b[3][2], vz, 0, 0, 0);
            dA0 = __builtin_amdgcn_mfma_f32_16x16x32_f16(a1, b[0][1], dA0, 0, 0, 0);
            dA1 = __builtin_amdgcn_mfma_f32_16x16x32_f16(a1, b[1][1], dA1, 0, 0, 0);
            dA2 = __builtin_amdgcn_mfma_f32_16x16x32_f16(a1, b[2][1], dA2, 0, 0, 0);
            dA3 = __builtin_amdgcn_mfma_f32_16x16x32_f16(a1, b[3][1], dA3, 0, 0, 0);
            dB0 = __builtin_amdgcn_mfma_f32_16x16x32_f16(a3, b[0][3], dB0, 0, 0, 0);
            dB1 = __builtin_amdgcn_mfma_f32_16x16x32_f16(a3, b[1][3], dB1, 0, 0, 0);
            dB2 = __builtin_amdgcn_mfma_f32_16x16x32_f16(a3, b[2][3], dB2, 0, 0, 0);
            dB3 = __builtin_amdgcn_mfma_f32_16x16x32_f16(a3, b[3][3], dB3, 0, 0, 0);

            // Lanes 0..15, reg 0 = row 0 = the matvec result per gate.
            const float4 zb = zcur[s];
            const float zi = dA0[0] + dB0[0] + zb.x;
            const float zf = dA1[0] + dB1[0] + zb.y;
            const float zg = dA2[0] + dB2[0] + zb.z;
            const float zo = dA3[0] + dB3[0] + zb.w;
            const float gi = fast_sigmoid(zi);
            const float gf = fast_sigmoid(zf);
            const float gg = fast_tanh(zg);
            const float go = fast_sigmoid(zo);
            c = gf * c + gi * gg;         // lanes 16-63: finite garbage, unused
            const float h = go * fast_tanh(c);
            hreg[s] = h;
            if (lane16) h_db[wb][u] = (_Float16)h;   // 2 f16/bank: free
            bar_lds();                    // one barrier per step, LDS-only
        }
#pragma unroll
        for (int s = 0; s < CH; ++s) zcur[s] = zfut[s];
    }
    if (lane16) {
#pragma unroll
        for (int s = 0; s < CH; ++s)
            hs[(BSEQ - CH + s) * HIDD + u] = hreg[s];
    }
}

// ---------------------------------------------------------------------------
// Kernel 3: final FC. out[t][n] = dot(hs[t], w_fc[n]) + b_fc[n].
// ---------------------------------------------------------------------------
__global__ void fc_kernel(const float* __restrict__ hs,
                          const float* __restrict__ w_fc,
                          const float* __restrict__ b_fc,
                          float* __restrict__ out) {
    const int gid = blockIdx.x * blockDim.x + threadIdx.x;
    if (gid >= BSEQ * NTAR) return;
    const int n = gid & (NTAR - 1);
    const int t = gid >> 4;
    const float4* __restrict__ hr = (const float4*)(hs + t * HIDD);
    const float4* __restrict__ wr = (const float4*)(w_fc + n * HIDD);
    float acc = 0.f;
#pragma unroll
    for (int k = 0; k < HIDD / 4; ++k) {
        float4 h = hr[k];
        float4 wv = wr[k];
        acc += h.x * wv.x + h.y * wv.y + h.z * wv.z + h.w * wv.w;
    }
    out[gid] = acc + b_fc[n];
}

// ---------------------------------------------------------------------------
extern "C" void kernel_launch(void* const* d_in, const int* in_sizes, int n_in,
                              void* d_out, int out_size, void* d_ws, size_t ws_size,
                              hipStream_t stream) {
    const int*   x    = (const int*)d_in[0];
    const float* emb  = (const float*)d_in[1];
    const float* w_ih = (const float*)d_in[2];
    const float* w_hh = (const float*)d_in[3];
    const float* b_ih = (const float*)d_in[4];
    const float* b_hh = (const float*)d_in[5];
    const float* w_fc = (const float*)d_in[6];
    const float* b_fc = (const float*)d_in[7];
    float* out = (float*)d_out;

    // Workspace: zxT (4096*512 f32 = 8 MB) | hs (4096*128 f32 = 2 MB)
    float* zxT = (float*)d_ws;
    float* hs  = zxT + (size_t)BSEQ * G4;

    input_proj_kernel<<<BSEQ, G4, 0, stream>>>(x, emb, w_ih, b_ih, b_hh, zxT);
    lstm_seq_kernel<<<1, 512, 0, stream>>>(zxT, w_hh, hs);
    fc_kernel<<<(BSEQ * NTAR + 255) / 256, 256, 0, stream>>>(hs, w_fc, b_fc, out);
}

// Round 19
// 2063.137 us; speedup vs baseline: 1.0088x; 1.0088x over previous
//
#include <hip/hip_runtime.h>
#include <math.h>

#define EMBD 128
#define HIDD 128
#define NTAR 16
#define BSEQ 4096
#define G4   512
#define CH   8            // zx load / hs store batch (amortizes barrier cost)

typedef _Float16 v8h __attribute__((ext_vector_type(8)));
typedef float    v4f __attribute__((ext_vector_type(4)));

__device__ __forceinline__ float fast_sigmoid(float z) {
    return __builtin_amdgcn_rcpf(1.f + __expf(-z));
}
__device__ __forceinline__ float fast_tanh(float z) {
    return 1.f - 2.f * __builtin_amdgcn_rcpf(1.f + __expf(2.f * z));
}

// Raw workgroup barrier WITHOUT the __syncthreads vmcnt(0) drain.
// Cross-wave dependency per step is ONLY h_db (LDS): lgkmcnt(0) before
// s_barrier orders ds_write -> barrier -> ds_read. Global zx prefetch
// loads / hs stores stay in flight across the barrier.
// SAFETY: R4 vs R5 (bar_lds vs __syncthreads) bit-identical; R11/R18 PASSED.
__device__ __forceinline__ void bar_lds() {
    asm volatile("s_waitcnt lgkmcnt(0)" ::: "memory");
    __builtin_amdgcn_s_barrier();
    asm volatile("" ::: "memory");
}

// ---------------------------------------------------------------------------
// Kernel 1: input projection, transposed layout (fp32 — zx precision anchor).
// zxT[(t*128 + u)*4 + g] = dot(emb[x[t]], w_ih[g*128+u]) + b_ih + b_hh
// ---------------------------------------------------------------------------
__global__ void input_proj_kernel(const int* __restrict__ x,
                                  const float* __restrict__ emb,
                                  const float* __restrict__ w_ih,
                                  const float* __restrict__ b_ih,
                                  const float* __restrict__ b_hh,
                                  float* __restrict__ zxT) {
    const int t = blockIdx.x;
    const int j = threadIdx.x;            // 0..511
    const int u = j >> 2;
    const int g = j & 3;
    const int row = g * HIDD + u;
    const int idx = x[t];
    const float4* __restrict__ er = (const float4*)(emb + (long long)idx * EMBD);
    const float4* __restrict__ wr = (const float4*)(w_ih + row * EMBD);
    float acc = 0.f;
#pragma unroll
    for (int k = 0; k < EMBD / 4; ++k) {
        float4 e = er[k];
        float4 w = wr[k];
        acc += e.x * w.x + e.y * w.y + e.z * w.z + e.w * w.w;
    }
    zxT[(t * HIDD + u) * 4 + g] = acc + b_ih[row] + b_hh[row];
}

// ---------------------------------------------------------------------------
// Kernel 2: sequential LSTM via MFMA. 512 threads (8 waves, 2/SIMD).
// R19: R11/R18-verified dataflow + GATE-CRITICAL-PATH REORDER:
//   o-gate's MFMA chains (dA3/dB3) issue LAST; the c-update + tanh(c)
//   dependent chain (~40 cyc, needs only z_{i,f,g}) computes while the
//   o-chains drain the matrix pipe. Identical per-chain arithmetic and
//   association -> bit-identical output to R18.
//
// Counter model (R18): step = 1071 cyc = ~508 matrix-pipe busy (47% duty,
// 128 MFMAs geometry-forced by M=1 matvec) + ~560 recurrence-forced serial
// latency (LDS h round-trip ~120, barrier ~40, gate chain ~60, tails/slop).
// Pipe-role hybrid (the 40% lever) abandoned: VALU dot deviates O(z)
// deterministically, unexplained after 13 audits + 4 runtime probes.
// fp8/i8 precision-blocked (h quant err 1.6e-2 / 4e-3 vs 1.8e-3 threshold).
//
// Wave w owns units [16w, 16w+16). B-frag (g,q), lane (n=l&15, qd=l>>4):
//   B[k=q*32+qd*8+j][n] = W_hh[g*128+U0+n][q*32+qd*8+j]  (8 f16, pinned).
// A-frag q: row 0 = h only; leaders (l&15==0) read h slices, other lanes
// read a zeroed 16B pad. D layout (m89): col=l&15, row=(l>>4)*4+reg ->
// row 0 in lanes 0..15 reg 0; gates stay in-lane. One barrier/step;
// h_db double-buffered on step parity; CH=8 batching.
// ---------------------------------------------------------------------------
__global__ __launch_bounds__(512, 2)
void lstm_seq_kernel(const float* __restrict__ zxT,
                     const float* __restrict__ w_hh,
                     float* __restrict__ hs) {
    __shared__ __align__(16) _Float16 h_db[2][HIDD];
    __shared__ __align__(16) _Float16 zpad[8];    // stays zero forever

    const int tid = threadIdx.x;
    const int l   = tid & 63;
    const int wv  = tid >> 6;            // 0..7
    const int n   = l & 15;              // unit-sub / MFMA col
    const int qd  = l >> 4;              // quad id 0..3
    const int U0  = wv * 16;             // this wave's unit block
    const int u   = U0 + n;
    const bool lane16 = (l < 16);        // holds valid z/h (row 0 lanes)

    // B-fragments: b[g][q], 8 f16 each = 64 VGPRs total. Pinned.
    v8h b[4][4];
#pragma unroll
    for (int g = 0; g < 4; ++g) {
#pragma unroll
        for (int q = 0; q < 4; ++q) {
            const float* __restrict__ wr =
                w_hh + (g * HIDD + u) * HIDD + q * 32 + qd * 8;
            v8h f;
#pragma unroll
            for (int j = 0; j < 8; ++j) f[j] = (_Float16)wr[j];
            b[g][q] = f;
        }
    }
#pragma unroll
    for (int g = 0; g < 4; ++g)
#pragma unroll
        for (int q = 0; q < 4; ++q)
            asm volatile("" : "+v"(b[g][q]));     // no rematerialization

    if (tid < HIDD) { h_db[0][tid] = (_Float16)0.f; h_db[1][tid] = (_Float16)0.f; }
    if (tid < 8)    zpad[tid] = (_Float16)0.f;

    // A-frag source addresses: leader lanes walk h, others pinned at zpad.
    const bool leader = (n == 0);
    const _Float16* abase0 = leader ? &h_db[0][qd * 8] : &zpad[0];
    const _Float16* abase1 = leader ? &h_db[1][qd * 8] : &zpad[0];
    const int astep = leader ? 32 : 0;            // halves per K-chunk

    float c = 0.f;
    float hreg[CH];
    float4 zcur[CH], zfut[CH];
    const float4* __restrict__ zx4 = (const float4*)zxT;
#pragma unroll
    for (int s = 0; s < CH; ++s) {
        zcur[s] = zx4[s * HIDD + u];     // lanes 16-63 duplicate lane n
        hreg[s] = 0.f;
    }
    __syncthreads();                     // init barrier: full drain is fine

    const v4f vz = {0.f, 0.f, 0.f, 0.f};

    for (int tc = 0; tc < BSEQ; tc += CH) {
        // Batch-store previous chunk's h (16 lanes/wave, coalesced 64B).
        if (lane16 && tc > 0) {
#pragma unroll
            for (int s = 0; s < CH; ++s)
                hs[(tc - CH + s) * HIDD + u] = hreg[s];
        }
        // Prefetch NEXT chunk's zx rows (stay in flight across bar_lds).
        {
            const int tn = (tc + CH < BSEQ) ? (tc + CH) : (BSEQ - CH);
#pragma unroll
            for (int s = 0; s < CH; ++s)
                zfut[s] = zx4[(tn + s) * HIDD + u];
        }

#pragma unroll
        for (int s = 0; s < CH; ++s) {
            const _Float16* ab = (s & 1) ? abase1 : abase0;
            const int wb = (s & 1) ^ 1;

            // A-frags: leaders read h slices, others read the zero pad.
            v8h a0 = *(const v8h*)(ab + 0 * astep);
            v8h a1 = *(const v8h*)(ab + 1 * astep);
            v8h a2 = *(const v8h*)(ab + 2 * astep);
            v8h a3 = *(const v8h*)(ab + 3 * astep);

            // i,f,g gate chains first (12 MFMAs, two depth-2 chains each):
            v4f dA0 = __builtin_amdgcn_mfma_f32_16x16x32_f16(a0, b[0][0], vz, 0, 0, 0);
            v4f dA1 = __builtin_amdgcn_mfma_f32_16x16x32_f16(a0, b[1][0], vz, 0, 0, 0);
            v4f dA2 = __builtin_amdgcn_mfma_f32_16x16x32_f16(a0, b[2][0], vz, 0, 0, 0);
            v4f dB0 = __builtin_amdgcn_mfma_f32_16x16x32_f16(a2, b[0][2], vz, 0, 0, 0);
            v4f dB1 = __builtin_amdgcn_mfma_f32_16x16x32_f16(a2, b[1][2], vz, 0, 0, 0);
            v4f dB2 = __builtin_amdgcn_mfma_f32_16x16x32_f16(a2, b[2][2], vz, 0, 0, 0);
            dA0 = __builtin_amdgcn_mfma_f32_16x16x32_f16(a1, b[0][1], dA0, 0, 0, 0);
            dA1 = __builtin_amdgcn_mfma_f32_16x16x32_f16(a1, b[1][1], dA1, 0, 0, 0);
            dA2 = __builtin_amdgcn_mfma_f32_16x16x32_f16(a1, b[2][1], dA2, 0, 0, 0);
            dB0 = __builtin_amdgcn_mfma_f32_16x16x32_f16(a3, b[0][3], dB0, 0, 0, 0);
            dB1 = __builtin_amdgcn_mfma_f32_16x16x32_f16(a3, b[1][3], dB1, 0, 0, 0);
            dB2 = __builtin_amdgcn_mfma_f32_16x16x32_f16(a3, b[2][3], dB2, 0, 0, 0);

            // o-gate chains issue LAST — their tail hides the c/tanh chain.
            v4f dA3 = __builtin_amdgcn_mfma_f32_16x16x32_f16(a0, b[3][0], vz, 0, 0, 0);
            v4f dB3 = __builtin_amdgcn_mfma_f32_16x16x32_f16(a2, b[3][2], vz, 0, 0, 0);
            dA3 = __builtin_amdgcn_mfma_f32_16x16x32_f16(a1, b[3][1], dA3, 0, 0, 0);
            dB3 = __builtin_amdgcn_mfma_f32_16x16x32_f16(a3, b[3][3], dB3, 0, 0, 0);

            // Early gate path: needs only z_{i,f,g} (~40-cyc dependent
            // chain overlapping the o-MFMA drain).
            const float4 zb = zcur[s];
            const float zi = dA0[0] + dB0[0] + zb.x;
            const float zf = dA1[0] + dB1[0] + zb.y;
            const float zg = dA2[0] + dB2[0] + zb.z;
            const float gi = fast_sigmoid(zi);
            const float gf = fast_sigmoid(zf);
            const float gg = fast_tanh(zg);
            c = gf * c + gi * gg;         // lanes 16-63: finite garbage, unused
            const float th = fast_tanh(c);

            // Late: o gate (last MFMA results) and h.
            const float zo = dA3[0] + dB3[0] + zb.w;
            const float go = fast_sigmoid(zo);
            const float h = go * th;
            hreg[s] = h;
            if (lane16) h_db[wb][u] = (_Float16)h;   // 2 f16/bank: free
            bar_lds();                    // one barrier per step, LDS-only
        }
#pragma unroll
        for (int s = 0; s < CH; ++s) zcur[s] = zfut[s];
    }
    if (lane16) {
#pragma unroll
        for (int s = 0; s < CH; ++s)
            hs[(BSEQ - CH + s) * HIDD + u] = hreg[s];
    }
}

// ---------------------------------------------------------------------------
// Kernel 3: final FC. out[t][n] = dot(hs[t], w_fc[n]) + b_fc[n].
// ---------------------------------------------------------------------------
__global__ void fc_kernel(const float* __restrict__ hs,
                          const float* __restrict__ w_fc,
                          const float* __restrict__ b_fc,
                          float* __restrict__ out) {
    const int gid = blockIdx.x * blockDim.x + threadIdx.x;
    if (gid >= BSEQ * NTAR) return;
    const int n = gid & (NTAR - 1);
    const int t = gid >> 4;
    const float4* __restrict__ hr = (const float4*)(hs + t * HIDD);
    const float4* __restrict__ wr = (const float4*)(w_fc + n * HIDD);
    float acc = 0.f;
#pragma unroll
    for (int k = 0; k < HIDD / 4; ++k) {
        float4 h = hr[k];
        float4 wv = wr[k];
        acc += h.x * wv.x + h.y * wv.y + h.z * wv.z + h.w * wv.w;
    }
    out[gid] = acc + b_fc[n];
}

// ---------------------------------------------------------------------------
extern "C" void kernel_launch(void* const* d_in, const int* in_sizes, int n_in,
                              void* d_out, int out_size, void* d_ws, size_t ws_size,
                              hipStream_t stream) {
    const int*   x    = (const int*)d_in[0];
    const float* emb  = (const float*)d_in[1];
    const float* w_ih = (const float*)d_in[2];
    const float* w_hh = (const float*)d_in[3];
    const float* b_ih = (const float*)d_in[4];
    const float* b_hh = (const float*)d_in[5];
    const float* w_fc = (const float*)d_in[6];
    const float* b_fc = (const float*)d_in[7];
    float* out = (float*)d_out;

    // Workspace: zxT (4096*512 f32 = 8 MB) | hs (4096*128 f32 = 2 MB)
    float* zxT = (float*)d_ws;
    float* hs  = zxT + (size_t)BSEQ * G4;

    input_proj_kernel<<<BSEQ, G4, 0, stream>>>(x, emb, w_ih, b_ih, b_hh, zxT);
    lstm_seq_kernel<<<1, 512, 0, stream>>>(zxT, w_hh, hs);
    fc_kernel<<<(BSEQ * NTAR + 255) / 256, 256, 0, stream>>>(hs, w_fc, b_fc, out);
}